// Round 1
// baseline (415.846 us; speedup 1.0000x reference)
//
#include <hip/hip_runtime.h>
#include <math.h>

// Problem constants (fixed by the harness/reference):
// B=2, S=8192, H=16, D=128, W=4 (window = W+1 = 5 taps)
constexpr int B = 2;
constexpr int S = 8192;
constexpr int H = 16;
constexpr int D = 128;
constexpr int W = 4;
constexpr int HD = H * D;          // 2048 floats = 8 KB per s step
constexpr int C = 16;              // consecutive s per 32-lane group (sliding window chunk)
constexpr float SCALE = 0.08838834764831845f;  // 1/sqrt(128)

// DPP butterfly add: x += lanepermute(x). CTRL: 0xB1=quad_perm(1,0,3,2)=xor1,
// 0x4E=quad_perm(2,3,0,1)=xor2, 0x141=row_half_mirror (acts as xor4 after
// xor1+xor2), 0x140=row_mirror (acts as xor8). All VALU-pipe, no DS.
template <int CTRL>
__device__ __forceinline__ float dpp_xadd(float x) {
    int r = __builtin_amdgcn_update_dpp(0, __float_as_int(x), CTRL, 0xF, 0xF, false);
    return x + __int_as_float(r);
}

// Reduce across the 32-lane group: 4 DPP steps (VALU) + one ds_swizzle xor16.
__device__ __forceinline__ float group_reduce32(float p) {
    p = dpp_xadd<0xB1>(p);    // xor 1
    p = dpp_xadd<0x4E>(p);    // xor 2
    p = dpp_xadd<0x141>(p);   // xor 4 (half-mirror)
    p = dpp_xadd<0x140>(p);   // xor 8 (mirror)
    int t = __builtin_amdgcn_ds_swizzle(__float_as_int(p), 0x401F);  // xor 16
    return p + __int_as_float(t);
}

// One 32-lane group per (b,h) processes C=16 CONSECUTIVE s with the 5-tap
// k/v/b window held in REGISTERS (sliding window): per output only 3 vector
// loads (q + new k + new v) instead of 11 — the 4 reused taps cost zero
// latency. Full unroll makes the window rotation (st+4)%5 compile-time.
// Block = 8 groups = 8 heads at the SAME s-chunk -> each step touches
// contiguous 4KB spans of q/k/v. blockIdx%8 = XCD, S split into 8 contiguous
// segments so halo reuse stays within one XCD's L2 (kept from round 2).
__global__ __launch_bounds__(256, 5) void gdr_kernel(
    const float* __restrict__ q, const float* __restrict__ k,
    const float* __restrict__ v, const float* __restrict__ a,
    const float* __restrict__ b, float* __restrict__ out)
{
    const int tid   = threadIdx.x;
    const int group = tid >> 5;   // 0..7 -> head within half
    const int lane  = tid & 31;

    const int bid = blockIdx.x;
    const int xcd = bid & 7;          // S-segment / XCD (round-robin heuristic)
    int r = bid >> 3;                 // 0..255
    const int cw = r & 63;  r >>= 6;  // chunk within segment (0..63)
    const int hh = r & 1;             // which half of the heads
    const int bb = r >> 1;            // batch
    const int h  = hh * 8 + group;
    const int s0 = xcd * (S / 8) + cw * C;

    const int d0 = lane * 4;
    // 32-bit element indices: max index = B*S*H*D = 33.5M < 2^31.
    const int eBase = ((bb * S + s0) * H + h) * D + d0;  // q/k/v/out elem idx at s0
    const int rBase = (bb * S + s0) * H + h;             // a/b row idx at s0

    // 5-slot sliding window in registers. slot(srow) = (srow - (s0-4)) % 5.
    float4 kw[5], vw[5];
    float  bw[5];
    if (s0 != 0) {
        // prologue: rows s0-4 .. s0-1 (all >= 12 here, valid)
#pragma unroll
        for (int i = 0; i < 4; ++i) {
            const int e = eBase - (4 - i) * HD;
            kw[i] = *(const float4*)(k + e);
            vw[i] = *(const float4*)(v + e);
            bw[i] = b[rBase - (4 - i) * H];
        }
    } else {
        // zero-padded history: k=v=0 makes those taps contribute exactly 0
#pragma unroll
        for (int i = 0; i < 4; ++i) {
            kw[i] = make_float4(0.f, 0.f, 0.f, 0.f);
            vw[i] = make_float4(0.f, 0.f, 0.f, 0.f);
            bw[i] = 0.f;
        }
    }

#pragma unroll
    for (int st = 0; st < C; ++st) {
        const int e   = eBase + st * HD;
        const int rb  = rBase + st * H;
        const int cur = (st + 4) % 5;      // slot for row s = s0+st

        kw[cur] = *(const float4*)(k + e);
        vw[cur] = *(const float4*)(v + e);
        bw[cur] = b[rb];
        float4 q4 = *(const float4*)(q + e);
        const float ai = a[rb];
        // fold the 1/sqrt(D) scale into q once (saves a mul per tap)
        q4.x *= SCALE; q4.y *= SCALE; q4.z *= SCALE; q4.w *= SCALE;

        // 5 partial dots from registers, then 5 independent reduces (ILP)
        float p[W + 1];
#pragma unroll
        for (int dl = 0; dl <= W; ++dl) {
            const int sl = (st + 4 - dl) % 5;
            float pp = q4.x * kw[sl].x + q4.y * kw[sl].y +
                       q4.z * kw[sl].z + q4.w * kw[sl].w;
            p[dl] = group_reduce32(pp);
        }

        float4 acc = make_float4(0.f, 0.f, 0.f, 0.f);
#pragma unroll
        for (int dl = 0; dl <= W; ++dl) {
            const int sl = (st + 4 - dl) % 5;
            const float g  = 1.0f / (1.0f + __expf(-(ai * bw[sl])));
            const float wg = p[dl] * g;
            acc.x += wg * vw[sl].x;
            acc.y += wg * vw[sl].y;
            acc.z += wg * vw[sl].z;
            acc.w += wg * vw[sl].w;
        }

        // position 0 is special-cased in the reference: out = v_0
        float4 res = acc;
        if (s0 + st == 0) res = vw[cur];   // only reachable at st==0, uniform
        *(float4*)(out + e) = res;
    }
}

extern "C" void kernel_launch(void* const* d_in, const int* in_sizes, int n_in,
                              void* d_out, int out_size, void* d_ws, size_t ws_size,
                              hipStream_t stream) {
    const float* q = (const float*)d_in[0];
    const float* k = (const float*)d_in[1];
    const float* v = (const float*)d_in[2];
    const float* a = (const float*)d_in[3];
    const float* b = (const float*)d_in[4];
    float* out = (float*)d_out;

    // blocks = B(2) * h-halves(2) * XCD segments(8) * chunks/segment(64) = 2048
    const int blocks = B * 2 * 8 * (S / 8 / C);
    gdr_kernel<<<blocks, 256, 0, stream>>>(q, k, v, a, b, out);
}